// Round 1
// 357.182 us; speedup vs baseline: 1.0135x; 1.0135x over previous
//
#include <hip/hip_runtime.h>

// ---------------------------------------------------------------------------
// MultiHeadAttention: B=4, S=2048, D=1024, H=16, Dh=64. FP32 I/O.
// cvt-all-to-bf16 -> merged QKV GEMM (1 dispatch, V writes Vt transposed) ->
// flash attention (fixed-max softmax; mask folded into MFMA C-init;
// double-buffered K/V prefetch, 1 barrier/iter; row-sum via ones-MFMA) ->
// out GEMM (f32 out).
// ---------------------------------------------------------------------------

typedef __bf16 bf16x8 __attribute__((ext_vector_type(8)));
typedef __bf16 bf16x4 __attribute__((ext_vector_type(4)));
typedef float  f32x4  __attribute__((ext_vector_type(4)));

#define LOG2E 1.44269504088896340736f
#define SCALE_Q (0.125f * LOG2E)      // 1/sqrt(64) * log2(e), folded into Q
#define MBIAS_L2 (-1.44269504e9f)     // -1e9 * log2(e)

__device__ inline unsigned short f2bf(float f) {  // RNE f32 -> bf16 bits
  unsigned int u = __float_as_uint(f);
  u = u + 0x7FFF + ((u >> 16) & 1);
  return (unsigned short)(u >> 16);
}
__device__ inline void gload16(const void* g, void* l) {  // 16B global->LDS DMA
  __builtin_amdgcn_global_load_lds(
      (const __attribute__((address_space(1))) void*)g,
      (__attribute__((address_space(3))) void*)l, 16, 0, 0);
}
__device__ inline bf16x8 cvt8(const float* p) {  // 8 f32 -> bf16x8
  float4 a = *(const float4*)p, b = *(const float4*)(p + 4);
  bf16x8 v;
  v[0] = (__bf16)a.x; v[1] = (__bf16)a.y; v[2] = (__bf16)a.z; v[3] = (__bf16)a.w;
  v[4] = (__bf16)b.x; v[5] = (__bf16)b.y; v[6] = (__bf16)b.z; v[7] = (__bf16)b.w;
  return v;
}

// ---------------------------------------------------------------------------
// cvt_all: f32 -> bf16, 7 jobs (q,k,v,Wq,Wk,Wv,Wo). grid (4096, 7), 256 thr.
// ---------------------------------------------------------------------------
struct CvtJob { const float* s; unsigned short* d; int n8; };
struct CvtJobs { CvtJob j[7]; };
__global__ void cvt_all(CvtJobs J) {
  CvtJob jb = J.j[blockIdx.y];
  int i = blockIdx.x * 256 + threadIdx.x;
  if (i < jb.n8) *(bf16x8*)(jb.d + (size_t)i * 8) = cvt8(jb.s + (size_t)i * 8);
}

// ---------------------------------------------------------------------------
// gemm_qkv: merged Q/K/V projections, one dispatch, grid (8, 64, 3).
// z in {0:Q, 1:K} swapped orientation (token-packed col-major stores);
// z==2 (V) normal orientation, writes Vt[(b*16+h)*64+d][s] directly.
// ---------------------------------------------------------------------------
struct ProjJob { const unsigned short* A; const unsigned short* W;
                 const float* bias; unsigned short* out; float scale; };
struct ProjJobs { ProjJob j[3]; };

__global__ __launch_bounds__(256, 2) void gemm_qkv(ProjJobs J) {
  __shared__ __align__(16) unsigned short Al[128 * 32];
  __shared__ __align__(16) unsigned short Wl[128 * 32];
  const int z = blockIdx.z;
  const ProjJob jb = J.j[z];
  const int tid = threadIdx.x, lane = tid & 63, w = tid >> 6;
  const int lid = lane & 15, lg = lane >> 4;
  const int c0 = blockIdx.x * 128, t0 = blockIdx.y * 128;
  const int wm = (w & 1) * 64, wn = (w >> 1) * 64;
  const unsigned short* Ml = (z == 2) ? Al : Wl;
  const unsigned short* Nl = (z == 2) ? Wl : Al;

  f32x4 acc[4][4];
#pragma unroll
  for (int i = 0; i < 4; i++)
#pragma unroll
    for (int j = 0; j < 4; j++) acc[i][j] = (f32x4){0.f, 0.f, 0.f, 0.f};

  for (int kt = 0; kt < 1024; kt += 32) {
    __syncthreads();
#pragma unroll
    for (int i = 0; i < 2; i++) {
      int c = i * 256 + tid, r = c >> 2, ko = (c & 3) * 8;
      gload16(jb.A + (size_t)(t0 + r) * 1024 + kt + ko, &Al[c * 8]);
      gload16(jb.W + (size_t)(c0 + r) * 1024 + kt + ko, &Wl[c * 8]);
    }
    __syncthreads();
    bf16x8 mf[4], nf[4];
#pragma unroll
    for (int mi = 0; mi < 4; mi++)
      mf[mi] = *(const bf16x8*)(&Ml[(wm + mi * 16 + lid) * 32 + lg * 8]);
#pragma unroll
    for (int ni = 0; ni < 4; ni++)
      nf[ni] = *(const bf16x8*)(&Nl[(wn + ni * 16 + lid) * 32 + lg * 8]);
#pragma unroll
    for (int mi = 0; mi < 4; mi++)
#pragma unroll
      for (int ni = 0; ni < 4; ni++)
        acc[mi][ni] = __builtin_amdgcn_mfma_f32_16x16x32_bf16(mf[mi], nf[ni],
                                                              acc[mi][ni], 0, 0, 0);
  }

  if (z < 2) {
    const float scale = jb.scale;
#pragma unroll
    for (int mi = 0; mi < 4; mi++) {
      int colb = c0 + wm + mi * 16 + lg * 4;
      float4 b4 = *(const float4*)(&jb.bias[colb]);
#pragma unroll
      for (int ni = 0; ni < 4; ni++) {
        int token = t0 + wn + ni * 16 + lid;
        ushort4 st;
        st.x = f2bf((acc[mi][ni][0] + b4.x) * scale);
        st.y = f2bf((acc[mi][ni][1] + b4.y) * scale);
        st.z = f2bf((acc[mi][ni][2] + b4.z) * scale);
        st.w = f2bf((acc[mi][ni][3] + b4.w) * scale);
        *(ushort4*)(&jb.out[(size_t)token * 1024 + colb]) = st;
      }
    }
  } else {
    const int b = t0 >> 11;
#pragma unroll
    for (int ni = 0; ni < 4; ni++) {
      int col = c0 + wn + ni * 16 + lid;
      int h = col >> 6, d = col & 63;
      float bv = jb.bias[col];
#pragma unroll
      for (int mi = 0; mi < 4; mi++) {
        int s = (t0 & 2047) + wm + mi * 16 + lg * 4;
        ushort4 st;
        st.x = f2bf(acc[mi][ni][0] + bv);
        st.y = f2bf(acc[mi][ni][1] + bv);
        st.z = f2bf(acc[mi][ni][2] + bv);
        st.w = f2bf(acc[mi][ni][3] + bv);
        *(ushort4*)(&jb.out[(size_t)((b * 16 + h) * 64 + d) * 2048 + s]) = st;
      }
    }
  }
}

// ---------------------------------------------------------------------------
// gemm_o: f32 C[token][col] = A_bf16 @ W_bf16^T + bias. grid (8, 64).
// ---------------------------------------------------------------------------
__global__ __launch_bounds__(256, 2) void gemm_o(
    const unsigned short* __restrict__ A, const unsigned short* __restrict__ W,
    const float* __restrict__ bias, float* __restrict__ C) {
  __shared__ __align__(16) unsigned short Al[128 * 32];
  __shared__ __align__(16) unsigned short Wl[128 * 32];
  const int tid = threadIdx.x, lane = tid & 63, w = tid >> 6;
  const int lid = lane & 15, lg = lane >> 4;
  const int c0 = blockIdx.x * 128, t0 = blockIdx.y * 128;
  const int wc = (w & 1) * 64, wt = (w >> 1) * 64;
  f32x4 acc[4][4];
#pragma unroll
  for (int i = 0; i < 4; i++)
#pragma unroll
    for (int j = 0; j < 4; j++) acc[i][j] = (f32x4){0.f, 0.f, 0.f, 0.f};

  for (int kt = 0; kt < 1024; kt += 32) {
    __syncthreads();
#pragma unroll
    for (int i = 0; i < 2; i++) {
      int c = i * 256 + tid, r = c >> 2, ko = (c & 3) * 8;
      gload16(A + (size_t)(t0 + r) * 1024 + kt + ko, &Al[c * 8]);
      gload16(W + (size_t)(c0 + r) * 1024 + kt + ko, &Wl[c * 8]);
    }
    __syncthreads();
    bf16x8 aw[4], bt[4];
#pragma unroll
    for (int mi = 0; mi < 4; mi++)
      aw[mi] = *(const bf16x8*)(&Wl[(wc + mi * 16 + lid) * 32 + lg * 8]);
#pragma unroll
    for (int ni = 0; ni < 4; ni++)
      bt[ni] = *(const bf16x8*)(&Al[(wt + ni * 16 + lid) * 32 + lg * 8]);
#pragma unroll
    for (int mi = 0; mi < 4; mi++)
#pragma unroll
      for (int ni = 0; ni < 4; ni++)
        acc[mi][ni] = __builtin_amdgcn_mfma_f32_16x16x32_bf16(aw[mi], bt[ni],
                                                              acc[mi][ni], 0, 0, 0);
  }
#pragma unroll
  for (int mi = 0; mi < 4; mi++) {
    int colb = c0 + wc + mi * 16 + lg * 4;
    float4 b4 = *(const float4*)(&bias[colb]);
#pragma unroll
    for (int ni = 0; ni < 4; ni++) {
      int token = t0 + wt + ni * 16 + lid;
      float4 st;
      st.x = acc[mi][ni][0] + b4.x;
      st.y = acc[mi][ni][1] + b4.y;
      st.z = acc[mi][ni][2] + b4.z;
      st.w = acc[mi][ni][3] + b4.w;
      *(float4*)(&C[(size_t)token * 1024 + colb]) = st;
    }
  }
}

// ---------------------------------------------------------------------------
// Flash attention v6: fixed-max softmax (scores bounded << fp32 exp range;
// masked keys: exp2(-1.4e9) == 0 exactly, bias folded into MFMA C-init).
//
// Changes vs v5 (counters: MfmaUtil 28%, VALUBusy 40%, ~32% stall):
//  * Double-buffered K/V: issue next tile's 8 global_load_lds BEFORE compute
//    of current tile; single barrier per iteration (its implicit
//    vmcnt(0)+lgkmcnt(0) drain is exactly the handoff we need). Loads get the
//    whole ~1500-cycle compute phase in flight instead of being drained
//    between two back-to-back barriers. LDS 72KB -> 2 blocks/CU.
//  * Row-sum l via ones-MFMA on the packed P fragments (k-permutation is
//    irrelevant for a sum): kills ps[] adds + shfl_xor chains (~96 VALU
//    ops/iter) at the cost of 8 MFMAs/iter on the 72%-idle matrix pipe.
//    Denominator now sums the SAME bf16-rounded p as the PV numerator.
//  * Mask bias table hoisted to a prologue (loop-invariant per block).
//  * s_setprio(1) around MFMA clusters (measured +4-7% on attn, m191).
// grid (16, 64), 256 thr (4 waves x 32 q rows).
// ---------------------------------------------------------------------------
__global__ __launch_bounds__(256, 2) void attn(
    const unsigned short* __restrict__ Qp,   // (B*S, 1024), pre-scaled
    const unsigned short* __restrict__ Kp,   // (B*S, 1024)
    const unsigned short* __restrict__ Vt,   // (B*H, 64, 2048)
    const int* __restrict__ maskp,           // (B, 2048)
    unsigned short* __restrict__ ctx) {      // (B*S, 1024)
  __shared__ __align__(16) unsigned short Klds[2][128 * 64];  // [key][d], XOR-swz
  __shared__ __align__(16) unsigned short Vlds[2][64 * 128];  // [d][key], XOR-swz
  __shared__ __align__(16) float mball[2048];                 // whole-row mask bias

  const int tid = threadIdx.x, lane = tid & 63, w = tid >> 6;
  const int lid = lane & 15, lg = lane >> 4;
  const int q0 = blockIdx.x * 128, bh = blockIdx.y;
  const int b = bh >> 4, h = bh & 15;
  const int wq = w * 32;
  const int x7 = lid & 7;  // XOR swizzle key (row&7 == lid&7 for all reads)

  const unsigned short* Kg = Kp + (size_t)(b * 2048) * 1024 + h * 64;
  const unsigned short* Vg = Vt + (size_t)bh * 64 * 2048;
  const int* mg = maskp + b * 2048;

  // mask prologue: bias for the whole key row (loop-invariant per block)
#pragma unroll
  for (int i = 0; i < 8; i++) {
    int idx = i * 256 + tid;
    mball[idx] = (mg[idx] == 0) ? MBIAS_L2 : 0.0f;
  }

  // Q fragments (B-operand of S^T): lane holds Q[q=nt*16+lid][d=ks*32+lg*8..]
  bf16x8 qf[2][2];
#pragma unroll
  for (int nt = 0; nt < 2; nt++)
#pragma unroll
    for (int ks = 0; ks < 2; ks++) {
      int qrow = b * 2048 + q0 + wq + nt * 16 + lid;
      qf[nt][ks] = *(const bf16x8*)(Qp + (size_t)qrow * 1024 + h * 64 + ks * 32 + lg * 8);
    }

  f32x4 Ot[4][2];  // O^T[d=dt*16+lg*4+r][q=qt*16+lid]
#pragma unroll
  for (int dt = 0; dt < 4; dt++)
#pragma unroll
    for (int qt = 0; qt < 2; qt++) Ot[dt][qt] = (f32x4){0.f, 0.f, 0.f, 0.f};
  f32x4 acc_l[2] = {(f32x4){0.f, 0.f, 0.f, 0.f}, (f32x4){0.f, 0.f, 0.f, 0.f}};
  bf16x8 ones8;
#pragma unroll
  for (int i = 0; i < 8; i++) ones8[i] = (__bf16)1.0f;

  // stage one 128-key tile (K 128x64, V^T 64x128) into buffer `bp`
  auto stage_kv = [&](unsigned short* Kl, unsigned short* Vl, int k0) {
#pragma unroll
    for (int i = 0; i < 4; i++) {
      int c = i * 256 + tid, r = c >> 3, gsw = (c & 7) ^ (r & 7);
      gload16(Kg + (size_t)(k0 + r) * 1024 + gsw * 8, Kl + c * 8);
    }
#pragma unroll
    for (int i = 0; i < 4; i++) {
      int c = i * 256 + tid, d = c >> 4, gsw = (c & 15) ^ (d & 7);
      gload16(Vg + (size_t)d * 2048 + k0 + gsw * 8, Vl + c * 8);
    }
  };

  stage_kv(Klds[0], Vlds[0], 0);
  __syncthreads();  // drains vmcnt(0): buf0 + mball + qf ready

  int cur = 0;
  for (int kt = 0; kt < 16; kt++) {
    // prefetch next tile into the other buffer; loads stay in flight across
    // the entire compute phase, drained only by the end-of-iter barrier.
    if (kt < 15) stage_kv(Klds[cur ^ 1], Vlds[cur ^ 1], (kt + 1) * 128);

    const unsigned short* Kl = Klds[cur];
    const unsigned short* Vl = Vlds[cur];
    const float* mb = mball + kt * 128;

    // two 64-key chunks (register-peak cap)
#pragma unroll
    for (int hf = 0; hf < 2; hf++) {
      // S^T chunk; C-init = mask bias (MFMA accumulates on top - free add)
      f32x4 accS[4][2];
#pragma unroll
      for (int mt = 0; mt < 4; mt++) {
        const f32x4 mb4 = *(const f32x4*)(&mb[hf * 64 + mt * 16 + lg * 4]);
        accS[mt][0] = mb4;
        accS[mt][1] = mb4;
      }
      __builtin_amdgcn_s_setprio(1);
#pragma unroll
      for (int ks = 0; ks < 2; ks++) {
        int koff = ((ks * 4 + lg) ^ x7) * 8;  // swizzled granule within row
#pragma unroll
        for (int mt = 0; mt < 4; mt++) {
          bf16x8 a = *(const bf16x8*)(&Kl[(hf * 64 + mt * 16 + lid) * 64 + koff]);
          accS[mt][0] = __builtin_amdgcn_mfma_f32_16x16x32_bf16(a, qf[0][ks], accS[mt][0], 0, 0, 0);
          accS[mt][1] = __builtin_amdgcn_mfma_f32_16x16x32_bf16(a, qf[1][ks], accS[mt][1], 0, 0, 0);
        }
      }
      __builtin_amdgcn_s_setprio(0);

      // fixed-max softmax: p = exp2(score); P packed into B-frags pb[c][qt]
      bf16x8 pb[2][2];
#pragma unroll
      for (int nt = 0; nt < 2; nt++) {
#pragma unroll
        for (int mt = 0; mt < 4; mt++) {
          int half = (mt & 1) * 4;
#pragma unroll
          for (int r = 0; r < 4; r++) {
            float p = __builtin_amdgcn_exp2f(accS[mt][nt][r]);
            pb[mt >> 1][nt][half + r] = (__bf16)p;
          }
        }
      }

      __builtin_amdgcn_s_setprio(1);
      // row-sum l += ones . P^T (k-permutation irrelevant for a sum; masked
      // keys contribute exactly 0). All C rows identical -> read reg 0 later.
#pragma unroll
      for (int c = 0; c < 2; c++)
#pragma unroll
        for (int qt = 0; qt < 2; qt++)
          acc_l[qt] = __builtin_amdgcn_mfma_f32_16x16x32_bf16(ones8, pb[c][qt], acc_l[qt], 0, 0, 0);

      // O^T += V^T . P^T; phys k=lg*8+j <-> key 32*cg+16*(j>=4)+lg*4+(j&3)
#pragma unroll
      for (int c = 0; c < 2; c++) {
        int cg = hf * 2 + c;
        int glo = ((4 * cg + (lg >> 1)) ^ x7) * 8 + (lg & 1) * 4;
        int ghi = ((4 * cg + 2 + (lg >> 1)) ^ x7) * 8 + (lg & 1) * 4;
#pragma unroll
        for (int dt = 0; dt < 4; dt++) {
          const unsigned short* vrow = &Vl[(dt * 16 + lid) * 128];
          bf16x4 lo = *(const bf16x4*)(&vrow[glo]);
          bf16x4 hi = *(const bf16x4*)(&vrow[ghi]);
          bf16x8 av = __builtin_shufflevector(lo, hi, 0, 1, 2, 3, 4, 5, 6, 7);
#pragma unroll
          for (int qt = 0; qt < 2; qt++)
            Ot[dt][qt] = __builtin_amdgcn_mfma_f32_16x16x32_bf16(av, pb[c][qt], Ot[dt][qt], 0, 0, 0);
        }
      }
      __builtin_amdgcn_s_setprio(0);
    }

    // single barrier: implicit vmcnt(0) lands the prefetch; implicit
    // lgkmcnt(0) retires this buffer's ds_reads before it is overwritten.
    __syncthreads();
    cur ^= 1;
  }

  // epilogue: ctx[q][h*64+d] = O^T/l ; d packed x4 -> 8B stores
#pragma unroll
  for (int qt = 0; qt < 2; qt++) {
    float inv = 1.0f / acc_l[qt][0];
    int qrow = b * 2048 + q0 + wq + qt * 16 + lid;
#pragma unroll
    for (int dt = 0; dt < 4; dt++) {
      ushort4 st;
      st.x = f2bf(Ot[dt][qt][0] * inv);
      st.y = f2bf(Ot[dt][qt][1] * inv);
      st.z = f2bf(Ot[dt][qt][2] * inv);
      st.w = f2bf(Ot[dt][qt][3] * inv);
      *(ushort4*)(&ctx[(size_t)qrow * 1024 + h * 64 + dt * 16 + lg * 4]) = st;
    }
  }
}

// ---------------------------------------------------------------------------
extern "C" void kernel_launch(void* const* d_in, const int* in_sizes, int n_in,
                              void* d_out, int out_size, void* d_ws, size_t ws_size,
                              hipStream_t stream) {
  const float* q  = (const float*)d_in[0];
  const float* k  = (const float*)d_in[1];
  const float* v  = (const float*)d_in[2];
  const int*   mk = (const int*)d_in[3];
  const float* Wq = (const float*)d_in[4];
  const float* bq = (const float*)d_in[5];
  const float* Wk = (const float*)d_in[6];
  const float* bk = (const float*)d_in[7];
  const float* Wv = (const float*)d_in[8];
  const float* bv = (const float*)d_in[9];
  const float* Wo = (const float*)d_in[10];
  const float* bo = (const float*)d_in[11];

  const size_t NTOK = (size_t)8192 * 1024;   // elements per activation tensor
  const size_t NW = (size_t)1024 * 1024;     // elements per weight

  unsigned short* qb  = (unsigned short*)d_ws;
  unsigned short* kb  = qb + NTOK;
  unsigned short* vb  = kb + NTOK;
  unsigned short* Qp  = vb + NTOK;
  unsigned short* Kp  = Qp + NTOK;
  unsigned short* Vt  = Kp + NTOK;
  unsigned short* Wqb = Vt + NTOK;
  unsigned short* Wkb = Wqb + NW;
  unsigned short* Wvb = Wkb + NW;
  unsigned short* Wob = Wvb + NW;
  unsigned short* ctx = qb;  // qb dead after QKV projections

  CvtJobs J;
  J.j[0] = {q, qb, (int)(NTOK / 8)};
  J.j[1] = {k, kb, (int)(NTOK / 8)};
  J.j[2] = {v, vb, (int)(NTOK / 8)};
  J.j[3] = {Wq, Wqb, (int)(NW / 8)};
  J.j[4] = {Wk, Wkb, (int)(NW / 8)};
  J.j[5] = {Wv, Wvb, (int)(NW / 8)};
  J.j[6] = {Wo, Wob, (int)(NW / 8)};
  cvt_all<<<dim3(4096, 7), 256, 0, stream>>>(J);

  ProjJobs P;
  P.j[0] = {qb, Wqb, bq, Qp, SCALE_Q};
  P.j[1] = {kb, Wkb, bk, Kp, 1.0f};
  P.j[2] = {vb, Wvb, bv, Vt, 1.0f};
  gemm_qkv<<<dim3(8, 64, 3), 256, 0, stream>>>(P);

  attn<<<dim3(16, 64), 256, 0, stream>>>(Qp, Kp, Vt, mk, ctx);
  gemm_o<<<dim3(8, 64), 256, 0, stream>>>(ctx, Wob, bo, (float*)d_out);
}

// Round 2
// 354.109 us; speedup vs baseline: 1.0223x; 1.0087x over previous
//
#include <hip/hip_runtime.h>

// ---------------------------------------------------------------------------
// MultiHeadAttention: B=4, S=2048, D=1024, H=16, Dh=64. FP32 I/O.
// cvt-all-to-bf16 -> merged QKV GEMM (1 dispatch, V writes Vt transposed) ->
// flash attention (fixed-max softmax; mask folded into MFMA C-init;
// 64-key double-buffered K/V prefetch, 1 barrier/tile, 40KB LDS = 4 blk/CU;
// row-sum via ones-MFMA) -> out GEMM (f32 out).
// ---------------------------------------------------------------------------

typedef __bf16 bf16x8 __attribute__((ext_vector_type(8)));
typedef __bf16 bf16x4 __attribute__((ext_vector_type(4)));
typedef float  f32x4  __attribute__((ext_vector_type(4)));

#define LOG2E 1.44269504088896340736f
#define SCALE_Q (0.125f * LOG2E)      // 1/sqrt(64) * log2(e), folded into Q
#define MBIAS_L2 (-1.44269504e9f)     // -1e9 * log2(e)

__device__ inline unsigned short f2bf(float f) {  // RNE f32 -> bf16 bits
  unsigned int u = __float_as_uint(f);
  u = u + 0x7FFF + ((u >> 16) & 1);
  return (unsigned short)(u >> 16);
}
__device__ inline void gload16(const void* g, void* l) {  // 16B global->LDS DMA
  __builtin_amdgcn_global_load_lds(
      (const __attribute__((address_space(1))) void*)g,
      (__attribute__((address_space(3))) void*)l, 16, 0, 0);
}
__device__ inline bf16x8 cvt8(const float* p) {  // 8 f32 -> bf16x8
  float4 a = *(const float4*)p, b = *(const float4*)(p + 4);
  bf16x8 v;
  v[0] = (__bf16)a.x; v[1] = (__bf16)a.y; v[2] = (__bf16)a.z; v[3] = (__bf16)a.w;
  v[4] = (__bf16)b.x; v[5] = (__bf16)b.y; v[6] = (__bf16)b.z; v[7] = (__bf16)b.w;
  return v;
}

// ---------------------------------------------------------------------------
// cvt_all: f32 -> bf16, 7 jobs (q,k,v,Wq,Wk,Wv,Wo). grid (4096, 7), 256 thr.
// ---------------------------------------------------------------------------
struct CvtJob { const float* s; unsigned short* d; int n8; };
struct CvtJobs { CvtJob j[7]; };
__global__ void cvt_all(CvtJobs J) {
  CvtJob jb = J.j[blockIdx.y];
  int i = blockIdx.x * 256 + threadIdx.x;
  if (i < jb.n8) *(bf16x8*)(jb.d + (size_t)i * 8) = cvt8(jb.s + (size_t)i * 8);
}

// ---------------------------------------------------------------------------
// gemm_qkv: merged Q/K/V projections, one dispatch, grid (8, 64, 3).
// z in {0:Q, 1:K} swapped orientation (token-packed col-major stores);
// z==2 (V) normal orientation, writes Vt[(b*16+h)*64+d][s] directly.
// ---------------------------------------------------------------------------
struct ProjJob { const unsigned short* A; const unsigned short* W;
                 const float* bias; unsigned short* out; float scale; };
struct ProjJobs { ProjJob j[3]; };

__global__ __launch_bounds__(256, 2) void gemm_qkv(ProjJobs J) {
  __shared__ __align__(16) unsigned short Al[128 * 32];
  __shared__ __align__(16) unsigned short Wl[128 * 32];
  const int z = blockIdx.z;
  const ProjJob jb = J.j[z];
  const int tid = threadIdx.x, lane = tid & 63, w = tid >> 6;
  const int lid = lane & 15, lg = lane >> 4;
  const int c0 = blockIdx.x * 128, t0 = blockIdx.y * 128;
  const int wm = (w & 1) * 64, wn = (w >> 1) * 64;
  const unsigned short* Ml = (z == 2) ? Al : Wl;
  const unsigned short* Nl = (z == 2) ? Wl : Al;

  f32x4 acc[4][4];
#pragma unroll
  for (int i = 0; i < 4; i++)
#pragma unroll
    for (int j = 0; j < 4; j++) acc[i][j] = (f32x4){0.f, 0.f, 0.f, 0.f};

  for (int kt = 0; kt < 1024; kt += 32) {
    __syncthreads();
#pragma unroll
    for (int i = 0; i < 2; i++) {
      int c = i * 256 + tid, r = c >> 2, ko = (c & 3) * 8;
      gload16(jb.A + (size_t)(t0 + r) * 1024 + kt + ko, &Al[c * 8]);
      gload16(jb.W + (size_t)(c0 + r) * 1024 + kt + ko, &Wl[c * 8]);
    }
    __syncthreads();
    bf16x8 mf[4], nf[4];
#pragma unroll
    for (int mi = 0; mi < 4; mi++)
      mf[mi] = *(const bf16x8*)(&Ml[(wm + mi * 16 + lid) * 32 + lg * 8]);
#pragma unroll
    for (int ni = 0; ni < 4; ni++)
      nf[ni] = *(const bf16x8*)(&Nl[(wn + ni * 16 + lid) * 32 + lg * 8]);
#pragma unroll
    for (int mi = 0; mi < 4; mi++)
#pragma unroll
      for (int ni = 0; ni < 4; ni++)
        acc[mi][ni] = __builtin_amdgcn_mfma_f32_16x16x32_bf16(mf[mi], nf[ni],
                                                              acc[mi][ni], 0, 0, 0);
  }

  if (z < 2) {
    const float scale = jb.scale;
#pragma unroll
    for (int mi = 0; mi < 4; mi++) {
      int colb = c0 + wm + mi * 16 + lg * 4;
      float4 b4 = *(const float4*)(&jb.bias[colb]);
#pragma unroll
      for (int ni = 0; ni < 4; ni++) {
        int token = t0 + wn + ni * 16 + lid;
        ushort4 st;
        st.x = f2bf((acc[mi][ni][0] + b4.x) * scale);
        st.y = f2bf((acc[mi][ni][1] + b4.y) * scale);
        st.z = f2bf((acc[mi][ni][2] + b4.z) * scale);
        st.w = f2bf((acc[mi][ni][3] + b4.w) * scale);
        *(ushort4*)(&jb.out[(size_t)token * 1024 + colb]) = st;
      }
    }
  } else {
    const int b = t0 >> 11;
#pragma unroll
    for (int ni = 0; ni < 4; ni++) {
      int col = c0 + wn + ni * 16 + lid;
      int h = col >> 6, d = col & 63;
      float bv = jb.bias[col];
#pragma unroll
      for (int mi = 0; mi < 4; mi++) {
        int s = (t0 & 2047) + wm + mi * 16 + lg * 4;
        ushort4 st;
        st.x = f2bf(acc[mi][ni][0] + bv);
        st.y = f2bf(acc[mi][ni][1] + bv);
        st.z = f2bf(acc[mi][ni][2] + bv);
        st.w = f2bf(acc[mi][ni][3] + bv);
        *(ushort4*)(&jb.out[(size_t)((b * 16 + h) * 64 + d) * 2048 + s]) = st;
      }
    }
  }
}

// ---------------------------------------------------------------------------
// gemm_o: f32 C[token][col] = A_bf16 @ W_bf16^T + bias. grid (8, 64).
// ---------------------------------------------------------------------------
__global__ __launch_bounds__(256, 2) void gemm_o(
    const unsigned short* __restrict__ A, const unsigned short* __restrict__ W,
    const float* __restrict__ bias, float* __restrict__ C) {
  __shared__ __align__(16) unsigned short Al[128 * 32];
  __shared__ __align__(16) unsigned short Wl[128 * 32];
  const int tid = threadIdx.x, lane = tid & 63, w = tid >> 6;
  const int lid = lane & 15, lg = lane >> 4;
  const int c0 = blockIdx.x * 128, t0 = blockIdx.y * 128;
  const int wc = (w & 1) * 64, wt = (w >> 1) * 64;
  f32x4 acc[4][4];
#pragma unroll
  for (int i = 0; i < 4; i++)
#pragma unroll
    for (int j = 0; j < 4; j++) acc[i][j] = (f32x4){0.f, 0.f, 0.f, 0.f};

  for (int kt = 0; kt < 1024; kt += 32) {
    __syncthreads();
#pragma unroll
    for (int i = 0; i < 2; i++) {
      int c = i * 256 + tid, r = c >> 2, ko = (c & 3) * 8;
      gload16(A + (size_t)(t0 + r) * 1024 + kt + ko, &Al[c * 8]);
      gload16(W + (size_t)(c0 + r) * 1024 + kt + ko, &Wl[c * 8]);
    }
    __syncthreads();
    bf16x8 aw[4], bt[4];
#pragma unroll
    for (int mi = 0; mi < 4; mi++)
      aw[mi] = *(const bf16x8*)(&Wl[(wc + mi * 16 + lid) * 32 + lg * 8]);
#pragma unroll
    for (int ni = 0; ni < 4; ni++)
      bt[ni] = *(const bf16x8*)(&Al[(wt + ni * 16 + lid) * 32 + lg * 8]);
#pragma unroll
    for (int mi = 0; mi < 4; mi++)
#pragma unroll
      for (int ni = 0; ni < 4; ni++)
        acc[mi][ni] = __builtin_amdgcn_mfma_f32_16x16x32_bf16(aw[mi], bt[ni],
                                                              acc[mi][ni], 0, 0, 0);
  }
#pragma unroll
  for (int mi = 0; mi < 4; mi++) {
    int colb = c0 + wc + mi * 16 + lg * 4;
    float4 b4 = *(const float4*)(&bias[colb]);
#pragma unroll
    for (int ni = 0; ni < 4; ni++) {
      int token = t0 + wt + ni * 16 + lid;
      float4 st;
      st.x = acc[mi][ni][0] + b4.x;
      st.y = acc[mi][ni][1] + b4.y;
      st.z = acc[mi][ni][2] + b4.z;
      st.w = acc[mi][ni][3] + b4.w;
      *(float4*)(&C[(size_t)token * 1024 + colb]) = st;
    }
  }
}

// ---------------------------------------------------------------------------
// Flash attention v7: fixed-max softmax (scores bounded << fp32 exp range;
// masked keys: exp2(-1.4e9) == 0 exactly, bias folded into MFMA C-init).
//
// Changes vs v6 (counters: MfmaUtil 33%, VALUBusy 40%, Occupancy 19.6% -
// latency/occupancy-bound, NOT pipe-bound; 72KB LDS capped us at 2 blk/CU):
//  * 64-key tiles instead of 128: same double-buffered single-barrier
//    pipeline, same per-compute work per key, but LDS 72KB -> 40KB =
//    4 blocks/CU (4 waves/SIMD). The quarter-rate exp2 chain of one wave
//    now has 3 other waves' MFMA/LDS phases to hide under.
//  * kt loop unrolled x2 so buffer bases are compile-time.
// grid (16, 64), 256 thr (4 waves x 32 q rows). LDS 40KB.
// ---------------------------------------------------------------------------
__global__ __launch_bounds__(256, 2) void attn(
    const unsigned short* __restrict__ Qp,   // (B*S, 1024), pre-scaled
    const unsigned short* __restrict__ Kp,   // (B*S, 1024)
    const unsigned short* __restrict__ Vt,   // (B*H, 64, 2048)
    const int* __restrict__ maskp,           // (B, 2048)
    unsigned short* __restrict__ ctx) {      // (B*S, 1024)
  __shared__ __align__(16) unsigned short Klds[2][64 * 64];  // [key][d], XOR-swz
  __shared__ __align__(16) unsigned short Vlds[2][64 * 64];  // [d][key], XOR-swz
  __shared__ __align__(16) float mball[2048];                // whole-row mask bias

  const int tid = threadIdx.x, lane = tid & 63, w = tid >> 6;
  const int lid = lane & 15, lg = lane >> 4;
  const int q0 = blockIdx.x * 128, bh = blockIdx.y;
  const int b = bh >> 4, h = bh & 15;
  const int wq = w * 32;
  const int x7 = lid & 7;  // XOR swizzle key (row&7 == lid&7 for all reads)

  const unsigned short* Kg = Kp + (size_t)(b * 2048) * 1024 + h * 64;
  const unsigned short* Vg = Vt + (size_t)bh * 64 * 2048;
  const int* mg = maskp + b * 2048;

  // mask prologue: bias for the whole key row (loop-invariant per block)
#pragma unroll
  for (int i = 0; i < 8; i++) {
    int idx = i * 256 + tid;
    mball[idx] = (mg[idx] == 0) ? MBIAS_L2 : 0.0f;
  }

  // Q fragments (B-operand of S^T): lane holds Q[q=nt*16+lid][d=ks*32+lg*8..]
  bf16x8 qf[2][2];
#pragma unroll
  for (int nt = 0; nt < 2; nt++)
#pragma unroll
    for (int ks = 0; ks < 2; ks++) {
      int qrow = b * 2048 + q0 + wq + nt * 16 + lid;
      qf[nt][ks] = *(const bf16x8*)(Qp + (size_t)qrow * 1024 + h * 64 + ks * 32 + lg * 8);
    }

  f32x4 Ot[4][2];  // O^T[d=dt*16+lg*4+r][q=qt*16+lid]
#pragma unroll
  for (int dt = 0; dt < 4; dt++)
#pragma unroll
    for (int qt = 0; qt < 2; qt++) Ot[dt][qt] = (f32x4){0.f, 0.f, 0.f, 0.f};
  f32x4 acc_l[2] = {(f32x4){0.f, 0.f, 0.f, 0.f}, (f32x4){0.f, 0.f, 0.f, 0.f}};
  bf16x8 ones8;
#pragma unroll
  for (int i = 0; i < 8; i++) ones8[i] = (__bf16)1.0f;

  // stage one 64-key tile (K 64x64, V^T 64x64) into the given buffer
  auto stage_kv = [&](unsigned short* Kl, unsigned short* Vl, int k0) {
#pragma unroll
    for (int i = 0; i < 2; i++) {
      int c = i * 256 + tid, r = c >> 3, gsw = (c & 7) ^ (r & 7);
      gload16(Kg + (size_t)(k0 + r) * 1024 + gsw * 8, Kl + c * 8);
    }
#pragma unroll
    for (int i = 0; i < 2; i++) {
      int c = i * 256 + tid, d = c >> 3, gsw = (c & 7) ^ (d & 7);
      gload16(Vg + (size_t)d * 2048 + k0 + gsw * 8, Vl + c * 8);
    }
  };

  // compute one 64-key tile from the given buffer
  auto compute_tile = [&](const unsigned short* Kl, const unsigned short* Vl,
                          int kt) {
    const float* mb = mball + kt * 64;
    // S^T; C-init = mask bias (MFMA accumulates on top - free add)
    f32x4 accS[4][2];
#pragma unroll
    for (int mt = 0; mt < 4; mt++) {
      const f32x4 mb4 = *(const f32x4*)(&mb[mt * 16 + lg * 4]);
      accS[mt][0] = mb4;
      accS[mt][1] = mb4;
    }
    __builtin_amdgcn_s_setprio(1);
#pragma unroll
    for (int ks = 0; ks < 2; ks++) {
      int koff = ((ks * 4 + lg) ^ x7) * 8;  // swizzled granule within row
#pragma unroll
      for (int mt = 0; mt < 4; mt++) {
        bf16x8 a = *(const bf16x8*)(&Kl[(mt * 16 + lid) * 64 + koff]);
        accS[mt][0] = __builtin_amdgcn_mfma_f32_16x16x32_bf16(a, qf[0][ks], accS[mt][0], 0, 0, 0);
        accS[mt][1] = __builtin_amdgcn_mfma_f32_16x16x32_bf16(a, qf[1][ks], accS[mt][1], 0, 0, 0);
      }
    }
    __builtin_amdgcn_s_setprio(0);

    // fixed-max softmax: p = exp2(score); P packed into B-frags pb[c][qt]
    bf16x8 pb[2][2];
#pragma unroll
    for (int nt = 0; nt < 2; nt++) {
#pragma unroll
      for (int mt = 0; mt < 4; mt++) {
        int half = (mt & 1) * 4;
#pragma unroll
        for (int r = 0; r < 4; r++) {
          float p = __builtin_amdgcn_exp2f(accS[mt][nt][r]);
          pb[mt >> 1][nt][half + r] = (__bf16)p;
        }
      }
    }

    __builtin_amdgcn_s_setprio(1);
    // row-sum l += ones . P^T (k-permutation irrelevant for a sum; masked
    // keys contribute exactly 0). All C rows identical -> read reg 0 later.
#pragma unroll
    for (int c = 0; c < 2; c++)
#pragma unroll
      for (int qt = 0; qt < 2; qt++)
        acc_l[qt] = __builtin_amdgcn_mfma_f32_16x16x32_bf16(ones8, pb[c][qt], acc_l[qt], 0, 0, 0);

    // O^T += V^T . P^T; phys k=lg*8+j <-> key 32*c+16*(j>=4)+lg*4+(j&3)
#pragma unroll
    for (int c = 0; c < 2; c++) {
      int glo = ((4 * c + (lg >> 1)) ^ x7) * 8 + (lg & 1) * 4;
      int ghi = ((4 * c + 2 + (lg >> 1)) ^ x7) * 8 + (lg & 1) * 4;
#pragma unroll
      for (int dt = 0; dt < 4; dt++) {
        const unsigned short* vrow = &Vl[(dt * 16 + lid) * 64];
        bf16x4 lo = *(const bf16x4*)(&vrow[glo]);
        bf16x4 hi = *(const bf16x4*)(&vrow[ghi]);
        bf16x8 av = __builtin_shufflevector(lo, hi, 0, 1, 2, 3, 4, 5, 6, 7);
#pragma unroll
        for (int qt = 0; qt < 2; qt++)
          Ot[dt][qt] = __builtin_amdgcn_mfma_f32_16x16x32_bf16(av, pb[c][qt], Ot[dt][qt], 0, 0, 0);
      }
    }
    __builtin_amdgcn_s_setprio(0);
  };

  stage_kv(Klds[0], Vlds[0], 0);
  __syncthreads();  // drains vmcnt(0): buf0 + mball + qf ready

  // x2-unrolled: buffer bases compile-time; prefetch issued BEFORE compute,
  // drained by the end-of-tile barrier (implicit vmcnt(0)+lgkmcnt(0)).
  for (int kt = 0; kt < 32; kt += 2) {
    stage_kv(Klds[1], Vlds[1], (kt + 1) * 64);
    compute_tile(Klds[0], Vlds[0], kt);
    __syncthreads();
    if (kt + 2 < 32) stage_kv(Klds[0], Vlds[0], (kt + 2) * 64);
    compute_tile(Klds[1], Vlds[1], kt + 1);
    __syncthreads();
  }

  // epilogue: ctx[q][h*64+d] = O^T/l ; d packed x4 -> 8B stores
#pragma unroll
  for (int qt = 0; qt < 2; qt++) {
    float inv = 1.0f / acc_l[qt][0];
    int qrow = b * 2048 + q0 + wq + qt * 16 + lid;
#pragma unroll
    for (int dt = 0; dt < 4; dt++) {
      ushort4 st;
      st.x = f2bf(Ot[dt][qt][0] * inv);
      st.y = f2bf(Ot[dt][qt][1] * inv);
      st.z = f2bf(Ot[dt][qt][2] * inv);
      st.w = f2bf(Ot[dt][qt][3] * inv);
      *(ushort4*)(&ctx[(size_t)qrow * 1024 + h * 64 + dt * 16 + lg * 4]) = st;
    }
  }
}

// ---------------------------------------------------------------------------
extern "C" void kernel_launch(void* const* d_in, const int* in_sizes, int n_in,
                              void* d_out, int out_size, void* d_ws, size_t ws_size,
                              hipStream_t stream) {
  const float* q  = (const float*)d_in[0];
  const float* k  = (const float*)d_in[1];
  const float* v  = (const float*)d_in[2];
  const int*   mk = (const int*)d_in[3];
  const float* Wq = (const float*)d_in[4];
  const float* bq = (const float*)d_in[5];
  const float* Wk = (const float*)d_in[6];
  const float* bk = (const float*)d_in[7];
  const float* Wv = (const float*)d_in[8];
  const float* bv = (const float*)d_in[9];
  const float* Wo = (const float*)d_in[10];
  const float* bo = (const float*)d_in[11];

  const size_t NTOK = (size_t)8192 * 1024;   // elements per activation tensor
  const size_t NW = (size_t)1024 * 1024;     // elements per weight

  unsigned short* qb  = (unsigned short*)d_ws;
  unsigned short* kb  = qb + NTOK;
  unsigned short* vb  = kb + NTOK;
  unsigned short* Qp  = vb + NTOK;
  unsigned short* Kp  = Qp + NTOK;
  unsigned short* Vt  = Kp + NTOK;
  unsigned short* Wqb = Vt + NTOK;
  unsigned short* Wkb = Wqb + NW;
  unsigned short* Wvb = Wkb + NW;
  unsigned short* Wob = Wvb + NW;
  unsigned short* ctx = qb;  // qb dead after QKV projections

  CvtJobs J;
  J.j[0] = {q, qb, (int)(NTOK / 8)};
  J.j[1] = {k, kb, (int)(NTOK / 8)};
  J.j[2] = {v, vb, (int)(NTOK / 8)};
  J.j[3] = {Wq, Wqb, (int)(NW / 8)};
  J.j[4] = {Wk, Wkb, (int)(NW / 8)};
  J.j[5] = {Wv, Wvb, (int)(NW / 8)};
  J.j[6] = {Wo, Wob, (int)(NW / 8)};
  cvt_all<<<dim3(4096, 7), 256, 0, stream>>>(J);

  ProjJobs P;
  P.j[0] = {qb, Wqb, bq, Qp, SCALE_Q};
  P.j[1] = {kb, Wkb, bk, Kp, 1.0f};
  P.j[2] = {vb, Wvb, bv, Vt, 1.0f};
  gemm_qkv<<<dim3(8, 64, 3), 256, 0, stream>>>(P);

  attn<<<dim3(16, 64), 256, 0, stream>>>(Qp, Kp, Vt, mk, ctx);
  gemm_o<<<dim3(8, 64), 256, 0, stream>>>(ctx, Wob, bo, (float*)d_out);
}